// Round 6
// baseline (289.916 us; speedup 1.0000x reference)
//
#include <hip/hip_runtime.h>
#include <hip/hip_fp16.h>
#include <cstddef>

#define NEG_SLOPE 0.2f
#define TILE 4096
#define CSR_CAP 4992

__device__ __forceinline__ float leaky(float x) { return x >= 0.f ? x : NEG_SLOPE * x; }

__device__ __forceinline__ int wave_iscan(int v, int lane) {
#pragma unroll
    for (int off = 1; off < 64; off <<= 1) {
        int t = __shfl_up(v, off);
        if (lane >= off) v += t;
    }
    return v;
}

// ---------------------------------------------------------------------------
// Register-blocked SGEMM + fused alpha dots. Input fp32 or fp16 (templated),
// output messages in fp16.
// ---------------------------------------------------------------------------
template <int F, typename IT>
__global__ __launch_bounds__(16 * (F / 8)) void gemm_alpha(
    const IT* __restrict__ x, const float* __restrict__ W,
    const float* __restrict__ a_s, const float* __restrict__ a_d,
    __half* __restrict__ hh, float* __restrict__ alphaS, float* __restrict__ alphaD,
    int N)
{
    constexpr int K = 128;
    constexpr int BK = 32;
    constexpr int BM = 64;
    constexpr int TM = 4;
    constexpr int TN = 8;
    constexpr int TC = F / TN;
    constexpr int THREADS = 16 * TC;

    __shared__ float As[BK][BM + 4];
    __shared__ float Bs[BK][F + 4];

    const int tid = threadIdx.x;
    const int tr = tid / TC;
    const int tc = tid % TC;
    const int rowb = blockIdx.x * BM;
    const int c0 = tc * 4;
    const int c1 = tc * 4 + F / 2;

    float acc[TM][TN];
#pragma unroll
    for (int m = 0; m < TM; m++)
#pragma unroll
        for (int n = 0; n < TN; n++) acc[m][n] = 0.f;

    for (int kt = 0; kt < K / BK; kt++) {
        for (int i = tid; i < BM * (BK / 4); i += THREADS) {
            int c4 = i & 7, r = i >> 3;
            int gr = rowb + r;
            float4 v = make_float4(0.f, 0.f, 0.f, 0.f);
            if (gr < N) {
                if constexpr (sizeof(IT) == 4) {
                    v = *(const float4*)((const float*)x + (size_t)gr * K + kt * BK + c4 * 4);
                } else {
                    const __half2* xp = (const __half2*)((const __half*)x + (size_t)gr * K + kt * BK + c4 * 4);
                    float2 f0 = __half22float2(xp[0]);
                    float2 f1 = __half22float2(xp[1]);
                    v = make_float4(f0.x, f0.y, f1.x, f1.y);
                }
            }
            As[c4 * 4 + 0][r] = v.x;
            As[c4 * 4 + 1][r] = v.y;
            As[c4 * 4 + 2][r] = v.z;
            As[c4 * 4 + 3][r] = v.w;
        }
        for (int i = tid; i < BK * (F / 4); i += THREADS) {
            int r = i / (F / 4), c4 = i % (F / 4);
            *(float4*)&Bs[r][c4 * 4] = *(const float4*)(W + (size_t)(kt * BK + r) * F + c4 * 4);
        }
        __syncthreads();

#pragma unroll 8
        for (int k = 0; k < BK; k++) {
            float a[TM], b[TN];
            *(float4*)&a[0] = *(float4*)&As[k][tr * 4];
            *(float4*)&b[0] = *(float4*)&Bs[k][c0];
            *(float4*)&b[4] = *(float4*)&Bs[k][c1];
#pragma unroll
            for (int m = 0; m < TM; m++)
#pragma unroll
                for (int n = 0; n < TN; n++)
                    acc[m][n] += a[m] * b[n];
        }
        __syncthreads();
    }

    float asv[TN], adv[TN];
    *(float4*)&asv[0] = *(const float4*)(a_s + c0);
    *(float4*)&asv[4] = *(const float4*)(a_s + c1);
    *(float4*)&adv[0] = *(const float4*)(a_d + c0);
    *(float4*)&adv[4] = *(const float4*)(a_d + c1);

#pragma unroll
    for (int m = 0; m < TM; m++) {
        int row = rowb + tr * 4 + m;
        bool ok = (row < N);
        if (ok) {
            __half2 h0 = __floats2half2_rn(acc[m][0], acc[m][1]);
            __half2 h1 = __floats2half2_rn(acc[m][2], acc[m][3]);
            __half2 h2 = __floats2half2_rn(acc[m][4], acc[m][5]);
            __half2 h3 = __floats2half2_rn(acc[m][6], acc[m][7]);
            __half2* hp0 = (__half2*)(hh + (size_t)row * F + c0);
            __half2* hp1 = (__half2*)(hh + (size_t)row * F + c1);
            hp0[0] = h0; hp0[1] = h1;
            hp1[0] = h2; hp1[1] = h3;
        }
        float ps = 0.f, pd = 0.f;
#pragma unroll
        for (int n = 0; n < TN; n++) {
            ps += acc[m][n] * asv[n];
            pd += acc[m][n] * adv[n];
        }
#pragma unroll
        for (int off = TC / 2; off >= 1; off >>= 1) {
            ps += __shfl_down(ps, off, TC);
            pd += __shfl_down(pd, off, TC);
        }
        if (ok && tc == 0) { alphaS[row] = ps; alphaD[row] = pd; }
    }
}

// ---------------------------------------------------------------------------
// CSR build, 3 kernels, no global atomics, no memset.
// tile_scatter: group each 4096-edge tile by bucket (dst>>8) in LDS, write
//   tile-local contiguous staging + per-(bucket,tile) count/offset matrix.
// bucket_offsets: scan matrix -> per-bucket global start + within-bucket
//   tile prefix.
// bucket_csr: per bucket, pull its runs into LDS, build node-level rowptr +
//   grouped src_sorted (contiguous, L2-local writes).
// ---------------------------------------------------------------------------
__global__ __launch_bounds__(256) void tile_scatter(
    const int* __restrict__ src, const int* __restrict__ dst,
    uint2* __restrict__ staging, int* __restrict__ cnts, int* __restrict__ loffs,
    int nbt, int E)
{
    __shared__ int lcnt[256], loff[256], ws[4];
    __shared__ uint2 pairs[TILE];
    const int tid = threadIdx.x;
    const int base = blockIdx.x * TILE;
    const int vt = min(TILE, E - base);

    lcnt[tid] = 0;
    __syncthreads();

    int d[TILE / 256], s[TILE / 256], r[TILE / 256];
#pragma unroll
    for (int j = 0; j < TILE / 256; j++) {
        int idx = base + j * 256 + tid;
        if (idx < E) {
            d[j] = dst[idx]; s[j] = src[idx];
            r[j] = atomicAdd(&lcnt[d[j] >> 8], 1);
        } else d[j] = -1;
    }
    __syncthreads();
    {
        int lane = tid & 63, wid = tid >> 6;
        int v = lcnt[tid];
        int incl = wave_iscan(v, lane);
        if (lane == 63) ws[wid] = incl;
        __syncthreads();
        int woff = 0;
        for (int w = 0; w < wid; w++) woff += ws[w];
        loff[tid] = woff + incl - v;
    }
    __syncthreads();
    cnts[tid * nbt + blockIdx.x] = lcnt[tid];
    loffs[tid * nbt + blockIdx.x] = loff[tid];
#pragma unroll
    for (int j = 0; j < TILE / 256; j++) {
        if (d[j] >= 0)
            pairs[loff[d[j] >> 8] + r[j]] = make_uint2((unsigned)d[j], (unsigned)s[j]);
    }
    __syncthreads();
    for (int slot = tid; slot < vt; slot += 256)
        staging[base + slot] = pairs[slot];
}

__global__ __launch_bounds__(256) void bucket_offsets(
    const int* __restrict__ cnts, int* __restrict__ pre,
    int* __restrict__ gstart, int* __restrict__ rowptrN,
    int nbt, int NB, int E)
{
    __shared__ int ws[4];
    const int b = threadIdx.x;
    int total = 0;
    if (b < NB) {
        for (int t = 0; t < nbt; t++) {
            pre[b * nbt + t] = total;
            total += cnts[b * nbt + t];
        }
    }
    int lane = b & 63, wid = b >> 6;
    int incl = wave_iscan(total, lane);
    if (lane == 63) ws[wid] = incl;
    __syncthreads();
    int woff = 0;
    for (int w = 0; w < wid; w++) woff += ws[w];
    int excl = woff + incl - total;
    gstart[b] = excl;
    if (b == 255) gstart[256] = excl + total;
    if (b == 0) *rowptrN = E;
}

__global__ __launch_bounds__(256) void bucket_csr(
    const uint2* __restrict__ staging, const int* __restrict__ pre,
    const int* __restrict__ loffs, const int* __restrict__ gstart,
    int* __restrict__ rowptr, int* __restrict__ src_sorted,
    int nbt, int N)
{
    __shared__ uint2 lp[CSR_CAP];
    __shared__ int pre_s[260];
    __shared__ int loffs_s[256];
    __shared__ int lcnt[256], loff[256], lfill[256], ws[4];
    const int tid = threadIdx.x;
    const int b = blockIdx.x;
    const int beg = gstart[b];
    const int len = gstart[b + 1] - beg;

    for (int t = tid; t < nbt; t += 256) {
        pre_s[t] = pre[b * nbt + t];
        loffs_s[t] = loffs[b * nbt + t];
    }
    if (tid == 0) pre_s[nbt] = len;
    lcnt[tid] = 0;
    __syncthreads();

    for (int p = tid; p < len; p += 256) {
        int lo = 0, hi = nbt;
        while (hi - lo > 1) { int mid = (lo + hi) >> 1; if (pre_s[mid] <= p) lo = mid; else hi = mid; }
        uint2 pr = staging[(size_t)lo * TILE + loffs_s[lo] + (p - pre_s[lo])];
        if (p < CSR_CAP) lp[p] = pr;
        atomicAdd(&lcnt[pr.x & 255], 1);
    }
    __syncthreads();
    {
        int lane = tid & 63, wid = tid >> 6;
        int v = lcnt[tid];
        int incl = wave_iscan(v, lane);
        if (lane == 63) ws[wid] = incl;
        __syncthreads();
        int woff = 0;
        for (int w = 0; w < wid; w++) woff += ws[w];
        int excl = woff + incl - v;
        loff[tid] = excl;
        lfill[tid] = excl;
        int node = (b << 8) + tid;
        if (node < N) rowptr[node] = beg + excl;
    }
    __syncthreads();
    for (int p = tid; p < len; p += 256) {
        uint2 pr;
        if (p < CSR_CAP) pr = lp[p];
        else {
            int lo = 0, hi = nbt;
            while (hi - lo > 1) { int mid = (lo + hi) >> 1; if (pre_s[mid] <= p) lo = mid; else hi = mid; }
            pr = staging[(size_t)lo * TILE + loffs_s[lo] + (p - pre_s[lo])];
        }
        int pos = atomicAdd(&lfill[pr.x & 255], 1);
        src_sorted[beg + pos] = (int)pr.y;
    }
}

// ---------------------------------------------------------------------------
// Fused per-destination aggregation: fp16 gather 16 B/lane, 2-wide unroll +
// src prefetch. Output fp16 (inter-layer) or fp32 (final), templated.
// ---------------------------------------------------------------------------
template <int F, bool RELU, typename OT>
__global__ __launch_bounds__(256) void gat_aggregate(
    const int* __restrict__ rowptr, const int* __restrict__ src_sorted,
    const __half* __restrict__ hh, const float* __restrict__ aS,
    const float* __restrict__ aD, const float* __restrict__ bias,
    OT* __restrict__ out, int N)
{
    constexpr int LPE = F / 8;          // lanes per edge (16 or 8)
    constexpr int EPW = 64 / LPE;       // edge slots per wave (4 or 8)

    const int i = blockIdx.x * 4 + (threadIdx.x >> 6);
    if (i >= N) return;
    const int lane = threadIdx.x & 63;
    const int sub = lane / LPE;
    const int l = lane % LPE;

    const float adi = aD[i];
    const int start = rowptr[i];
    const int end = rowptr[i + 1];

    float acc0[8], acc1[8];
#pragma unroll
    for (int q = 0; q < 8; q++) { acc0[q] = 0.f; acc1[q] = 0.f; }
    float den0 = 0.f, den1 = 0.f;

    int e0 = start + sub;
    int e1 = e0 + EPW;
    int s0 = (e0 < end) ? src_sorted[e0] : -1;
    int s1 = (e1 < end) ? src_sorted[e1] : -1;

    while (s0 >= 0) {
        int n0 = (e0 + 2 * EPW < end) ? src_sorted[e0 + 2 * EPW] : -1;
        int n1 = (e1 + 2 * EPW < end) ? src_sorted[e1 + 2 * EPW] : -1;
        {
            float w = __expf(leaky(aS[s0] + adi));
            uint4 u = *(const uint4*)(hh + (size_t)s0 * F + l * 8);
            const __half2* hp = (const __half2*)&u;
#pragma unroll
            for (int q = 0; q < 4; q++) {
                float2 f = __half22float2(hp[q]);
                acc0[q * 2]     += w * f.x;
                acc0[q * 2 + 1] += w * f.y;
            }
            den0 += w;
        }
        if (s1 >= 0) {
            float w = __expf(leaky(aS[s1] + adi));
            uint4 u = *(const uint4*)(hh + (size_t)s1 * F + l * 8);
            const __half2* hp = (const __half2*)&u;
#pragma unroll
            for (int q = 0; q < 4; q++) {
                float2 f = __half22float2(hp[q]);
                acc1[q * 2]     += w * f.x;
                acc1[q * 2 + 1] += w * f.y;
            }
            den1 += w;
        }
        e0 += 2 * EPW; e1 += 2 * EPW;
        s0 = n0; s1 = n1;
    }

    float acc[8];
#pragma unroll
    for (int q = 0; q < 8; q++) acc[q] = acc0[q] + acc1[q];
    float denom = den0 + den1;

#pragma unroll
    for (int off = 32; off >= LPE; off >>= 1) {
#pragma unroll
        for (int q = 0; q < 8; q++) acc[q] += __shfl_down(acc[q], off);
        denom += __shfl_down(denom, off);
    }

    if (sub == 0) {
        float wsf = __expf(leaky(aS[i] + adi));
        uint4 u = *(const uint4*)(hh + (size_t)i * F + l * 8);
        const __half2* hp = (const __half2*)&u;
        float inv = 1.f / (denom + wsf);
        float4 b0 = *(const float4*)(bias + l * 8);
        float4 b1 = *(const float4*)(bias + l * 8 + 4);
        float o[8];
#pragma unroll
        for (int q = 0; q < 4; q++) {
            float2 f = __half22float2(hp[q]);
            o[q * 2]     = (acc[q * 2]     + wsf * f.x) * inv;
            o[q * 2 + 1] = (acc[q * 2 + 1] + wsf * f.y) * inv;
        }
        o[0] += b0.x; o[1] += b0.y; o[2] += b0.z; o[3] += b0.w;
        o[4] += b1.x; o[5] += b1.y; o[6] += b1.z; o[7] += b1.w;
        if (RELU) {
#pragma unroll
            for (int q = 0; q < 8; q++) o[q] = fmaxf(o[q], 0.f);
        }
        if constexpr (sizeof(OT) == 2) {
            __half2 qh[4];
            qh[0] = __floats2half2_rn(o[0], o[1]);
            qh[1] = __floats2half2_rn(o[2], o[3]);
            qh[2] = __floats2half2_rn(o[4], o[5]);
            qh[3] = __floats2half2_rn(o[6], o[7]);
            *(uint4*)((__half*)out + (size_t)i * F + l * 8) = *(uint4*)qh;
        } else {
            *(float4*)((float*)out + (size_t)i * F + l * 8)     = make_float4(o[0], o[1], o[2], o[3]);
            *(float4*)((float*)out + (size_t)i * F + l * 8 + 4) = make_float4(o[4], o[5], o[6], o[7]);
        }
    }
}

extern "C" void kernel_launch(void* const* d_in, const int* in_sizes, int n_in,
                              void* d_out, int out_size, void* d_ws, size_t ws_size,
                              hipStream_t stream)
{
    const float* x   = (const float*)d_in[0];
    const int*   ei  = (const int*)d_in[1];
    const float* W1  = (const float*)d_in[2];
    const float* aS1 = (const float*)d_in[3];
    const float* aD1 = (const float*)d_in[4];
    const float* b1  = (const float*)d_in[5];
    const float* W2  = (const float*)d_in[6];
    const float* aS2 = (const float*)d_in[7];
    const float* aD2 = (const float*)d_in[8];
    const float* b2  = (const float*)d_in[9];

    const int K = 128, F1 = 128, F2 = 64;
    const int N = in_sizes[0] / K;
    const int E = in_sizes[1] / 2;
    const int* src = ei;
    const int* dst = ei + E;

    const int Np = (N + 4) & ~3;
    const int NB = (N + 255) >> 8;              // buckets of 256 nodes (196)
    const int nbt = (E + TILE - 1) / TILE;      // edge tiles (196), <= 256

    char* wsb = (char*)d_ws;
    int* cnts       = (int*)wsb;    wsb += (size_t)256 * nbt * 4;
    int* loffs      = (int*)wsb;    wsb += (size_t)256 * nbt * 4;
    int* pre        = (int*)wsb;    wsb += (size_t)256 * nbt * 4;
    int* gstart     = (int*)wsb;    wsb += 272 * 4;
    int* rowptr     = (int*)wsb;    wsb += (size_t)(Np + 4) * 4;
    uint2* staging  = (uint2*)wsb;  wsb += (size_t)nbt * TILE * 8;
    int* src_sorted = (int*)wsb;    wsb += (size_t)E * 4;
    __half* hh1     = (__half*)wsb; wsb += (size_t)N * F1 * 2;
    __half* x2h     = (__half*)wsb; wsb += (size_t)N * F1 * 2;
    __half* hh2     = (__half*)wsb; wsb += (size_t)N * F2 * 2;
    float* as_      = (float*)wsb;  wsb += (size_t)Np * 4;
    float* ad_      = (float*)wsb;  wsb += (size_t)Np * 4;

    dim3 blk(256);

    // ---- layer-1 GEMM (independent of CSR) ----
    gemm_alpha<F1, float><<<dim3((N + 63) / 64), dim3(256), 0, stream>>>(
        x, W1, aS1, aD1, hh1, as_, ad_, N);

    // ---- CSR build ----
    tile_scatter<<<dim3(nbt), blk, 0, stream>>>(src, dst, staging, cnts, loffs, nbt, E);
    bucket_offsets<<<dim3(1), blk, 0, stream>>>(cnts, pre, gstart, rowptr + N, nbt, NB, E);
    bucket_csr<<<dim3(NB), blk, 0, stream>>>(staging, pre, loffs, gstart,
                                             rowptr, src_sorted, nbt, N);

    // ---- layer 1 aggregate -> fp16 x2 ----
    gat_aggregate<F1, true, __half><<<dim3((N + 3) / 4), blk, 0, stream>>>(
        rowptr, src_sorted, hh1, as_, ad_, b1, x2h, N);

    // ---- layer 2 ----
    gemm_alpha<F2, __half><<<dim3((N + 63) / 64), dim3(128), 0, stream>>>(
        x2h, W2, aS2, aD2, hh2, as_, ad_, N);
    gat_aggregate<F2, false, float><<<dim3((N + 3) / 4), blk, 0, stream>>>(
        rowptr, src_sorted, hh2, as_, ad_, b2, (float*)d_out, N);
}

// Round 7
// 240.806 us; speedup vs baseline: 1.2039x; 1.2039x over previous
//
#include <hip/hip_runtime.h>
#include <hip/hip_fp16.h>
#include <cstddef>

#define NEG_SLOPE 0.2f
#define TILE 4096
#define CSR_CAP 4992

__device__ __forceinline__ float leaky(float x) { return x >= 0.f ? x : NEG_SLOPE * x; }

__device__ __forceinline__ int wave_iscan(int v, int lane) {
#pragma unroll
    for (int off = 1; off < 64; off <<= 1) {
        int t = __shfl_up(v, off);
        if (lane >= off) v += t;
    }
    return v;
}

// ---------------------------------------------------------------------------
// Register-blocked SGEMM + fused alpha dots. Input fp32 or fp16 (templated),
// output messages in fp16.
// ---------------------------------------------------------------------------
template <int F, typename IT>
__global__ __launch_bounds__(16 * (F / 8)) void gemm_alpha(
    const IT* __restrict__ x, const float* __restrict__ W,
    const float* __restrict__ a_s, const float* __restrict__ a_d,
    __half* __restrict__ hh, float* __restrict__ alphaS, float* __restrict__ alphaD,
    int N)
{
    constexpr int K = 128;
    constexpr int BK = 32;
    constexpr int BM = 64;
    constexpr int TM = 4;
    constexpr int TN = 8;
    constexpr int TC = F / TN;
    constexpr int THREADS = 16 * TC;

    __shared__ float As[BK][BM + 4];
    __shared__ float Bs[BK][F + 4];

    const int tid = threadIdx.x;
    const int tr = tid / TC;
    const int tc = tid % TC;
    const int rowb = blockIdx.x * BM;
    const int c0 = tc * 4;
    const int c1 = tc * 4 + F / 2;

    float acc[TM][TN];
#pragma unroll
    for (int m = 0; m < TM; m++)
#pragma unroll
        for (int n = 0; n < TN; n++) acc[m][n] = 0.f;

    for (int kt = 0; kt < K / BK; kt++) {
        for (int i = tid; i < BM * (BK / 4); i += THREADS) {
            int c4 = i & 7, r = i >> 3;
            int gr = rowb + r;
            float4 v = make_float4(0.f, 0.f, 0.f, 0.f);
            if (gr < N) {
                if constexpr (sizeof(IT) == 4) {
                    v = *(const float4*)((const float*)x + (size_t)gr * K + kt * BK + c4 * 4);
                } else {
                    const __half2* xp = (const __half2*)((const __half*)x + (size_t)gr * K + kt * BK + c4 * 4);
                    float2 f0 = __half22float2(xp[0]);
                    float2 f1 = __half22float2(xp[1]);
                    v = make_float4(f0.x, f0.y, f1.x, f1.y);
                }
            }
            As[c4 * 4 + 0][r] = v.x;
            As[c4 * 4 + 1][r] = v.y;
            As[c4 * 4 + 2][r] = v.z;
            As[c4 * 4 + 3][r] = v.w;
        }
        for (int i = tid; i < BK * (F / 4); i += THREADS) {
            int r = i / (F / 4), c4 = i % (F / 4);
            *(float4*)&Bs[r][c4 * 4] = *(const float4*)(W + (size_t)(kt * BK + r) * F + c4 * 4);
        }
        __syncthreads();

#pragma unroll 8
        for (int k = 0; k < BK; k++) {
            float a[TM], b[TN];
            *(float4*)&a[0] = *(float4*)&As[k][tr * 4];
            *(float4*)&b[0] = *(float4*)&Bs[k][c0];
            *(float4*)&b[4] = *(float4*)&Bs[k][c1];
#pragma unroll
            for (int m = 0; m < TM; m++)
#pragma unroll
                for (int n = 0; n < TN; n++)
                    acc[m][n] += a[m] * b[n];
        }
        __syncthreads();
    }

    float asv[TN], adv[TN];
    *(float4*)&asv[0] = *(const float4*)(a_s + c0);
    *(float4*)&asv[4] = *(const float4*)(a_s + c1);
    *(float4*)&adv[0] = *(const float4*)(a_d + c0);
    *(float4*)&adv[4] = *(const float4*)(a_d + c1);

#pragma unroll
    for (int m = 0; m < TM; m++) {
        int row = rowb + tr * 4 + m;
        bool ok = (row < N);
        if (ok) {
            __half2 h0 = __floats2half2_rn(acc[m][0], acc[m][1]);
            __half2 h1 = __floats2half2_rn(acc[m][2], acc[m][3]);
            __half2 h2 = __floats2half2_rn(acc[m][4], acc[m][5]);
            __half2 h3 = __floats2half2_rn(acc[m][6], acc[m][7]);
            __half2* hp0 = (__half2*)(hh + (size_t)row * F + c0);
            __half2* hp1 = (__half2*)(hh + (size_t)row * F + c1);
            hp0[0] = h0; hp0[1] = h1;
            hp1[0] = h2; hp1[1] = h3;
        }
        float ps = 0.f, pd = 0.f;
#pragma unroll
        for (int n = 0; n < TN; n++) {
            ps += acc[m][n] * asv[n];
            pd += acc[m][n] * adv[n];
        }
#pragma unroll
        for (int off = TC / 2; off >= 1; off >>= 1) {
            ps += __shfl_down(ps, off, TC);
            pd += __shfl_down(pd, off, TC);
        }
        if (ok && tc == 0) { alphaS[row] = ps; alphaD[row] = pd; }
    }
}

// ---------------------------------------------------------------------------
// CSR build, 4 small kernels, no global atomics, no memset.
// ---------------------------------------------------------------------------
__global__ __launch_bounds__(256) void tile_scatter(
    const int* __restrict__ src, const int* __restrict__ dst,
    uint2* __restrict__ staging, int* __restrict__ cnts, int* __restrict__ loffs,
    int nbt, int E)
{
    __shared__ int lcnt[256], loff[256], ws[4];
    __shared__ uint2 pairs[TILE];
    const int tid = threadIdx.x;
    const int base = blockIdx.x * TILE;
    const int vt = min(TILE, E - base);

    lcnt[tid] = 0;
    __syncthreads();

    int d[TILE / 256], s[TILE / 256], r[TILE / 256];
#pragma unroll
    for (int j = 0; j < TILE / 256; j++) {
        int idx = base + j * 256 + tid;
        if (idx < E) {
            d[j] = dst[idx]; s[j] = src[idx];
            r[j] = atomicAdd(&lcnt[d[j] >> 8], 1);
        } else d[j] = -1;
    }
    __syncthreads();
    {
        int lane = tid & 63, wid = tid >> 6;
        int v = lcnt[tid];
        int incl = wave_iscan(v, lane);
        if (lane == 63) ws[wid] = incl;
        __syncthreads();
        int woff = 0;
        for (int w = 0; w < wid; w++) woff += ws[w];
        loff[tid] = woff + incl - v;
    }
    __syncthreads();
    cnts[tid * nbt + blockIdx.x] = lcnt[tid];
    loffs[tid * nbt + blockIdx.x] = loff[tid];
#pragma unroll
    for (int j = 0; j < TILE / 256; j++) {
        if (d[j] >= 0)
            pairs[loff[d[j] >> 8] + r[j]] = make_uint2((unsigned)d[j], (unsigned)s[j]);
    }
    __syncthreads();
    for (int slot = tid; slot < vt; slot += 256)
        staging[base + slot] = pairs[slot];
}

// Per-bucket parallel exclusive scan over its tile counts (block b = bucket b).
__global__ __launch_bounds__(256) void pre_scan(
    const int* __restrict__ cnts, int* __restrict__ pre,
    int* __restrict__ btot, int nbt)
{
    __shared__ int ws[4];
    __shared__ int carry;
    const int b = blockIdx.x;
    const int tid = threadIdx.x;
    if (tid == 0) carry = 0;
    __syncthreads();
    for (int base = 0; base < nbt; base += 256) {
        int t = base + tid;
        int v = (t < nbt) ? cnts[b * nbt + t] : 0;
        int lane = tid & 63, wid = tid >> 6;
        int incl = wave_iscan(v, lane);
        if (lane == 63) ws[wid] = incl;
        __syncthreads();
        int woff = carry;
        for (int w = 0; w < wid; w++) woff += ws[w];
        if (t < nbt) pre[b * nbt + t] = woff + incl - v;
        __syncthreads();
        if (tid == 0) carry += ws[0] + ws[1] + ws[2] + ws[3];
        __syncthreads();
    }
    if (tid == 0) btot[b] = carry;
}

// Single tiny block: scan bucket totals -> gstart.
__global__ __launch_bounds__(256) void gstart_scan(
    const int* __restrict__ btot, int* __restrict__ gstart,
    int* __restrict__ rowptrN, int NB, int E)
{
    __shared__ int ws[4];
    const int b = threadIdx.x;
    int v = (b < NB) ? btot[b] : 0;
    int lane = b & 63, wid = b >> 6;
    int incl = wave_iscan(v, lane);
    if (lane == 63) ws[wid] = incl;
    __syncthreads();
    int woff = 0;
    for (int w = 0; w < wid; w++) woff += ws[w];
    int excl = woff + incl - v;
    gstart[b] = excl;
    if (b == 255) gstart[256] = excl + v;
    if (b == 0) *rowptrN = E;
}

__global__ __launch_bounds__(256) void bucket_csr(
    const uint2* __restrict__ staging, const int* __restrict__ pre,
    const int* __restrict__ loffs, const int* __restrict__ gstart,
    int* __restrict__ rowptr, int* __restrict__ src_sorted,
    int nbt, int N)
{
    __shared__ uint2 lp[CSR_CAP];
    __shared__ int pre_s[260];
    __shared__ int loffs_s[256];
    __shared__ int lcnt[256], loff[256], lfill[256], ws[4];
    const int tid = threadIdx.x;
    const int b = blockIdx.x;
    const int beg = gstart[b];
    const int len = gstart[b + 1] - beg;

    for (int t = tid; t < nbt; t += 256) {
        pre_s[t] = pre[b * nbt + t];
        loffs_s[t] = loffs[b * nbt + t];
    }
    if (tid == 0) pre_s[nbt] = len;
    lcnt[tid] = 0;
    __syncthreads();

    for (int p = tid; p < len; p += 256) {
        int lo = 0, hi = nbt;
        while (hi - lo > 1) { int mid = (lo + hi) >> 1; if (pre_s[mid] <= p) lo = mid; else hi = mid; }
        uint2 pr = staging[(size_t)lo * TILE + loffs_s[lo] + (p - pre_s[lo])];
        if (p < CSR_CAP) lp[p] = pr;
        atomicAdd(&lcnt[pr.x & 255], 1);
    }
    __syncthreads();
    {
        int lane = tid & 63, wid = tid >> 6;
        int v = lcnt[tid];
        int incl = wave_iscan(v, lane);
        if (lane == 63) ws[wid] = incl;
        __syncthreads();
        int woff = 0;
        for (int w = 0; w < wid; w++) woff += ws[w];
        int excl = woff + incl - v;
        loff[tid] = excl;
        lfill[tid] = excl;
        int node = (b << 8) + tid;
        if (node < N) rowptr[node] = beg + excl;
    }
    __syncthreads();
    for (int p = tid; p < len; p += 256) {
        uint2 pr;
        if (p < CSR_CAP) pr = lp[p];
        else {
            int lo = 0, hi = nbt;
            while (hi - lo > 1) { int mid = (lo + hi) >> 1; if (pre_s[mid] <= p) lo = mid; else hi = mid; }
            pr = staging[(size_t)lo * TILE + loffs_s[lo] + (p - pre_s[lo])];
        }
        int pos = atomicAdd(&lfill[pr.x & 255], 1);
        src_sorted[beg + pos] = (int)pr.y;
    }
}

// ---------------------------------------------------------------------------
// Fused per-destination aggregation: fp16 gather 16 B/lane, 2-wide unroll +
// src prefetch. Output fp16 (inter-layer) or fp32 (final), templated.
// ---------------------------------------------------------------------------
template <int F, bool RELU, typename OT>
__global__ __launch_bounds__(256) void gat_aggregate(
    const int* __restrict__ rowptr, const int* __restrict__ src_sorted,
    const __half* __restrict__ hh, const float* __restrict__ aS,
    const float* __restrict__ aD, const float* __restrict__ bias,
    OT* __restrict__ out, int N)
{
    constexpr int LPE = F / 8;          // lanes per edge (16 or 8)
    constexpr int EPW = 64 / LPE;       // edge slots per wave (4 or 8)

    const int i = blockIdx.x * 4 + (threadIdx.x >> 6);
    if (i >= N) return;
    const int lane = threadIdx.x & 63;
    const int sub = lane / LPE;
    const int l = lane % LPE;

    const float adi = aD[i];
    const int start = rowptr[i];
    const int end = rowptr[i + 1];

    float acc0[8], acc1[8];
#pragma unroll
    for (int q = 0; q < 8; q++) { acc0[q] = 0.f; acc1[q] = 0.f; }
    float den0 = 0.f, den1 = 0.f;

    int e0 = start + sub;
    int e1 = e0 + EPW;
    int s0 = (e0 < end) ? src_sorted[e0] : -1;
    int s1 = (e1 < end) ? src_sorted[e1] : -1;

    while (s0 >= 0) {
        int n0 = (e0 + 2 * EPW < end) ? src_sorted[e0 + 2 * EPW] : -1;
        int n1 = (e1 + 2 * EPW < end) ? src_sorted[e1 + 2 * EPW] : -1;
        {
            float w = __expf(leaky(aS[s0] + adi));
            uint4 u = *(const uint4*)(hh + (size_t)s0 * F + l * 8);
            const __half2* hp = (const __half2*)&u;
#pragma unroll
            for (int q = 0; q < 4; q++) {
                float2 f = __half22float2(hp[q]);
                acc0[q * 2]     += w * f.x;
                acc0[q * 2 + 1] += w * f.y;
            }
            den0 += w;
        }
        if (s1 >= 0) {
            float w = __expf(leaky(aS[s1] + adi));
            uint4 u = *(const uint4*)(hh + (size_t)s1 * F + l * 8);
            const __half2* hp = (const __half2*)&u;
#pragma unroll
            for (int q = 0; q < 4; q++) {
                float2 f = __half22float2(hp[q]);
                acc1[q * 2]     += w * f.x;
                acc1[q * 2 + 1] += w * f.y;
            }
            den1 += w;
        }
        e0 += 2 * EPW; e1 += 2 * EPW;
        s0 = n0; s1 = n1;
    }

    float acc[8];
#pragma unroll
    for (int q = 0; q < 8; q++) acc[q] = acc0[q] + acc1[q];
    float denom = den0 + den1;

#pragma unroll
    for (int off = 32; off >= LPE; off >>= 1) {
#pragma unroll
        for (int q = 0; q < 8; q++) acc[q] += __shfl_down(acc[q], off);
        denom += __shfl_down(denom, off);
    }

    if (sub == 0) {
        float wsf = __expf(leaky(aS[i] + adi));
        uint4 u = *(const uint4*)(hh + (size_t)i * F + l * 8);
        const __half2* hp = (const __half2*)&u;
        float inv = 1.f / (denom + wsf);
        float4 b0 = *(const float4*)(bias + l * 8);
        float4 b1 = *(const float4*)(bias + l * 8 + 4);
        float o[8];
#pragma unroll
        for (int q = 0; q < 4; q++) {
            float2 f = __half22float2(hp[q]);
            o[q * 2]     = (acc[q * 2]     + wsf * f.x) * inv;
            o[q * 2 + 1] = (acc[q * 2 + 1] + wsf * f.y) * inv;
        }
        o[0] += b0.x; o[1] += b0.y; o[2] += b0.z; o[3] += b0.w;
        o[4] += b1.x; o[5] += b1.y; o[6] += b1.z; o[7] += b1.w;
        if (RELU) {
#pragma unroll
            for (int q = 0; q < 8; q++) o[q] = fmaxf(o[q], 0.f);
        }
        if constexpr (sizeof(OT) == 2) {
            __half2 qh[4];
            qh[0] = __floats2half2_rn(o[0], o[1]);
            qh[1] = __floats2half2_rn(o[2], o[3]);
            qh[2] = __floats2half2_rn(o[4], o[5]);
            qh[3] = __floats2half2_rn(o[6], o[7]);
            *(uint4*)((__half*)out + (size_t)i * F + l * 8) = *(uint4*)qh;
        } else {
            *(float4*)((float*)out + (size_t)i * F + l * 8)     = make_float4(o[0], o[1], o[2], o[3]);
            *(float4*)((float*)out + (size_t)i * F + l * 8 + 4) = make_float4(o[4], o[5], o[6], o[7]);
        }
    }
}

extern "C" void kernel_launch(void* const* d_in, const int* in_sizes, int n_in,
                              void* d_out, int out_size, void* d_ws, size_t ws_size,
                              hipStream_t stream)
{
    const float* x   = (const float*)d_in[0];
    const int*   ei  = (const int*)d_in[1];
    const float* W1  = (const float*)d_in[2];
    const float* aS1 = (const float*)d_in[3];
    const float* aD1 = (const float*)d_in[4];
    const float* b1  = (const float*)d_in[5];
    const float* W2  = (const float*)d_in[6];
    const float* aS2 = (const float*)d_in[7];
    const float* aD2 = (const float*)d_in[8];
    const float* b2  = (const float*)d_in[9];

    const int K = 128, F1 = 128, F2 = 64;
    const int N = in_sizes[0] / K;
    const int E = in_sizes[1] / 2;
    const int* src = ei;
    const int* dst = ei + E;

    const int Np = (N + 4) & ~3;
    const int NB = (N + 255) >> 8;              // buckets of 256 nodes (196)
    const int nbt = (E + TILE - 1) / TILE;      // edge tiles (196)

    char* wsb = (char*)d_ws;
    int* cnts       = (int*)wsb;    wsb += (size_t)256 * nbt * 4;
    int* loffs      = (int*)wsb;    wsb += (size_t)256 * nbt * 4;
    int* pre        = (int*)wsb;    wsb += (size_t)256 * nbt * 4;
    int* btot       = (int*)wsb;    wsb += 256 * 4;
    int* gstart     = (int*)wsb;    wsb += 272 * 4;
    int* rowptr     = (int*)wsb;    wsb += (size_t)(Np + 4) * 4;
    uint2* staging  = (uint2*)wsb;  wsb += (size_t)nbt * TILE * 8;
    int* src_sorted = (int*)wsb;    wsb += (size_t)E * 4;
    __half* hh1     = (__half*)wsb; wsb += (size_t)N * F1 * 2;
    __half* x2h     = (__half*)wsb; wsb += (size_t)N * F1 * 2;
    __half* hh2     = (__half*)wsb; wsb += (size_t)N * F2 * 2;
    float* as_      = (float*)wsb;  wsb += (size_t)Np * 4;
    float* ad_      = (float*)wsb;  wsb += (size_t)Np * 4;

    dim3 blk(256);

    // ---- layer-1 GEMM (independent of CSR) ----
    gemm_alpha<F1, float><<<dim3((N + 63) / 64), dim3(256), 0, stream>>>(
        x, W1, aS1, aD1, hh1, as_, ad_, N);

    // ---- CSR build ----
    tile_scatter<<<dim3(nbt), blk, 0, stream>>>(src, dst, staging, cnts, loffs, nbt, E);
    pre_scan<<<dim3(NB), blk, 0, stream>>>(cnts, pre, btot, nbt);
    gstart_scan<<<dim3(1), blk, 0, stream>>>(btot, gstart, rowptr + N, NB, E);
    bucket_csr<<<dim3(NB), blk, 0, stream>>>(staging, pre, loffs, gstart,
                                             rowptr, src_sorted, nbt, N);

    // ---- layer 1 aggregate -> fp16 x2 ----
    gat_aggregate<F1, true, __half><<<dim3((N + 3) / 4), blk, 0, stream>>>(
        rowptr, src_sorted, hh1, as_, ad_, b1, x2h, N);

    // ---- layer 2 ----
    gemm_alpha<F2, __half><<<dim3((N + 63) / 64), dim3(128), 0, stream>>>(
        x2h, W2, aS2, aD2, hh2, as_, ad_, N);
    gat_aggregate<F2, false, float><<<dim3((N + 3) / 4), blk, 0, stream>>>(
        rowptr, src_sorted, hh2, as_, ad_, b2, (float*)d_out, N);
}

// Round 8
// 227.178 us; speedup vs baseline: 1.2762x; 1.0600x over previous
//
#include <hip/hip_runtime.h>
#include <hip/hip_fp16.h>
#include <cstddef>

#define NEG_SLOPE 0.2f
#define TILE 4096
#define CSR_CAP 6144   // per-bucket LDS cache (packed u32); avg bucket ~4096

__device__ __forceinline__ float leaky(float x) { return x >= 0.f ? x : NEG_SLOPE * x; }

__device__ __forceinline__ int wave_iscan(int v, int lane) {
#pragma unroll
    for (int off = 1; off < 64; off <<= 1) {
        int t = __shfl_up(v, off);
        if (lane >= off) v += t;
    }
    return v;
}

// ---------------------------------------------------------------------------
// Register-blocked SGEMM + fused alpha dots. Input fp32 or fp16 (templated),
// output messages in fp16.
// ---------------------------------------------------------------------------
template <int F, typename IT>
__global__ __launch_bounds__(16 * (F / 8)) void gemm_alpha(
    const IT* __restrict__ x, const float* __restrict__ W,
    const float* __restrict__ a_s, const float* __restrict__ a_d,
    __half* __restrict__ hh, float* __restrict__ alphaS, float* __restrict__ alphaD,
    int N)
{
    constexpr int K = 128;
    constexpr int BK = 32;
    constexpr int BM = 64;
    constexpr int TM = 4;
    constexpr int TN = 8;
    constexpr int TC = F / TN;
    constexpr int THREADS = 16 * TC;

    __shared__ float As[BK][BM + 4];
    __shared__ float Bs[BK][F + 4];

    const int tid = threadIdx.x;
    const int tr = tid / TC;
    const int tc = tid % TC;
    const int rowb = blockIdx.x * BM;
    const int c0 = tc * 4;
    const int c1 = tc * 4 + F / 2;

    float acc[TM][TN];
#pragma unroll
    for (int m = 0; m < TM; m++)
#pragma unroll
        for (int n = 0; n < TN; n++) acc[m][n] = 0.f;

    for (int kt = 0; kt < K / BK; kt++) {
        for (int i = tid; i < BM * (BK / 4); i += THREADS) {
            int c4 = i & 7, r = i >> 3;
            int gr = rowb + r;
            float4 v = make_float4(0.f, 0.f, 0.f, 0.f);
            if (gr < N) {
                if constexpr (sizeof(IT) == 4) {
                    v = *(const float4*)((const float*)x + (size_t)gr * K + kt * BK + c4 * 4);
                } else {
                    const __half2* xp = (const __half2*)((const __half*)x + (size_t)gr * K + kt * BK + c4 * 4);
                    float2 f0 = __half22float2(xp[0]);
                    float2 f1 = __half22float2(xp[1]);
                    v = make_float4(f0.x, f0.y, f1.x, f1.y);
                }
            }
            As[c4 * 4 + 0][r] = v.x;
            As[c4 * 4 + 1][r] = v.y;
            As[c4 * 4 + 2][r] = v.z;
            As[c4 * 4 + 3][r] = v.w;
        }
        for (int i = tid; i < BK * (F / 4); i += THREADS) {
            int r = i / (F / 4), c4 = i % (F / 4);
            *(float4*)&Bs[r][c4 * 4] = *(const float4*)(W + (size_t)(kt * BK + r) * F + c4 * 4);
        }
        __syncthreads();

#pragma unroll 8
        for (int k = 0; k < BK; k++) {
            float a[TM], b[TN];
            *(float4*)&a[0] = *(float4*)&As[k][tr * 4];
            *(float4*)&b[0] = *(float4*)&Bs[k][c0];
            *(float4*)&b[4] = *(float4*)&Bs[k][c1];
#pragma unroll
            for (int m = 0; m < TM; m++)
#pragma unroll
                for (int n = 0; n < TN; n++)
                    acc[m][n] += a[m] * b[n];
        }
        __syncthreads();
    }

    float asv[TN], adv[TN];
    *(float4*)&asv[0] = *(const float4*)(a_s + c0);
    *(float4*)&asv[4] = *(const float4*)(a_s + c1);
    *(float4*)&adv[0] = *(const float4*)(a_d + c0);
    *(float4*)&adv[4] = *(const float4*)(a_d + c1);

#pragma unroll
    for (int m = 0; m < TM; m++) {
        int row = rowb + tr * 4 + m;
        bool ok = (row < N);
        if (ok) {
            __half2 h0 = __floats2half2_rn(acc[m][0], acc[m][1]);
            __half2 h1 = __floats2half2_rn(acc[m][2], acc[m][3]);
            __half2 h2 = __floats2half2_rn(acc[m][4], acc[m][5]);
            __half2 h3 = __floats2half2_rn(acc[m][6], acc[m][7]);
            __half2* hp0 = (__half2*)(hh + (size_t)row * F + c0);
            __half2* hp1 = (__half2*)(hh + (size_t)row * F + c1);
            hp0[0] = h0; hp0[1] = h1;
            hp1[0] = h2; hp1[1] = h3;
        }
        float ps = 0.f, pd = 0.f;
#pragma unroll
        for (int n = 0; n < TN; n++) {
            ps += acc[m][n] * asv[n];
            pd += acc[m][n] * adv[n];
        }
#pragma unroll
        for (int off = TC / 2; off >= 1; off >>= 1) {
            ps += __shfl_down(ps, off, TC);
            pd += __shfl_down(pd, off, TC);
        }
        if (ok && tc == 0) { alphaS[row] = ps; alphaD[row] = pd; }
    }
}

// ---------------------------------------------------------------------------
// CSR build (R5 structure, packed u32 staging: pair = (dst<<16)|src, valid
// because N < 65536). bucket = dst>>8.
// ---------------------------------------------------------------------------
__global__ __launch_bounds__(256) void bucket_count(
    const int* __restrict__ dst, int* __restrict__ gcnt, int E)
{
    __shared__ int lcnt[256];
    const int tid = threadIdx.x;
    const int base = blockIdx.x * TILE;
    lcnt[tid] = 0;
    __syncthreads();
#pragma unroll
    for (int j = 0; j < TILE / 256; j++) {
        int idx = base + j * 256 + tid;
        if (idx < E) atomicAdd(&lcnt[dst[idx] >> 8], 1);
    }
    __syncthreads();
    int c = lcnt[tid];
    if (c > 0) atomicAdd(&gcnt[tid], c);
}

__global__ __launch_bounds__(256) void bucket_scan(
    const int* __restrict__ gcnt, int* __restrict__ gstart,
    int* __restrict__ gfill, int NB, int* __restrict__ rowptrN, int E)
{
    __shared__ int ws[4];
    int tid = threadIdx.x, lane = tid & 63, wid = tid >> 6;
    int v = (tid < NB) ? gcnt[tid] : 0;
    int incl = wave_iscan(v, lane);
    if (lane == 63) ws[wid] = incl;
    __syncthreads();
    int woff = 0;
    for (int w = 0; w < wid; w++) woff += ws[w];
    int excl = woff + incl - v;
    if (tid <= NB) gstart[tid] = excl;
    if (tid < NB) gfill[tid] = excl;
    if (tid == 255) gstart[256] = excl + v;
    if (tid == 0) *rowptrN = E;
}

__global__ __launch_bounds__(256) void bucket_scatter(
    const int* __restrict__ src, const int* __restrict__ dst,
    int* __restrict__ gfill, unsigned* __restrict__ staging, int E)
{
    __shared__ int lcnt[256];
    __shared__ int loff[256];
    __shared__ int gbase[256];
    __shared__ int ws[4];
    __shared__ unsigned pairs[TILE];
    __shared__ unsigned char bkt[TILE];

    const int tid = threadIdx.x;
    const int base = blockIdx.x * TILE;
    const int vt = min(TILE, E - base);

    lcnt[tid] = 0;
    __syncthreads();

    int d[TILE / 256], s[TILE / 256], r[TILE / 256];
#pragma unroll
    for (int j = 0; j < TILE / 256; j++) {
        int idx = base + j * 256 + tid;
        if (idx < E) {
            d[j] = dst[idx]; s[j] = src[idx];
            r[j] = atomicAdd(&lcnt[d[j] >> 8], 1);
        } else d[j] = -1;
    }
    __syncthreads();
    {
        int lane = tid & 63, wid = tid >> 6;
        int v = lcnt[tid];
        int incl = wave_iscan(v, lane);
        if (lane == 63) ws[wid] = incl;
        __syncthreads();
        int woff = 0;
        for (int w = 0; w < wid; w++) woff += ws[w];
        loff[tid] = woff + incl - v;
    }
    __syncthreads();
    {
        int c = lcnt[tid];
        if (c > 0) gbase[tid] = atomicAdd(&gfill[tid], c);
    }
    __syncthreads();
#pragma unroll
    for (int j = 0; j < TILE / 256; j++) {
        if (d[j] >= 0) {
            int b = d[j] >> 8;
            int slot = loff[b] + r[j];
            pairs[slot] = ((unsigned)d[j] << 16) | (unsigned)s[j];
            bkt[slot] = (unsigned char)b;
        }
    }
    __syncthreads();
    for (int slot = tid; slot < vt; slot += 256) {
        int b = bkt[slot];
        staging[gbase[b] + (slot - loff[b])] = pairs[slot];
    }
}

__global__ __launch_bounds__(256) void bucket_to_csr(
    const unsigned* __restrict__ staging, const int* __restrict__ gstart,
    int* __restrict__ rowptr, int* __restrict__ src_sorted, int N)
{
    __shared__ unsigned lp[CSR_CAP];
    __shared__ int lcnt[256], loff[256], lfill[256];
    __shared__ int ws[4];
    const int tid = threadIdx.x;
    const int b = blockIdx.x;
    const int beg = gstart[b], end = gstart[b + 1];
    const int len = end - beg;

    lcnt[tid] = 0;
    __syncthreads();
    for (int p = tid; p < len; p += 256) {
        unsigned u = staging[beg + p];
        if (p < CSR_CAP) lp[p] = u;
        atomicAdd(&lcnt[(u >> 16) & 255], 1);
    }
    __syncthreads();
    {
        int lane = tid & 63, wid = tid >> 6;
        int v = lcnt[tid];
        int incl = wave_iscan(v, lane);
        if (lane == 63) ws[wid] = incl;
        __syncthreads();
        int woff = 0;
        for (int w = 0; w < wid; w++) woff += ws[w];
        int excl = woff + incl - v;
        loff[tid] = excl;
        lfill[tid] = excl;
        int node = (b << 8) + tid;
        if (node < N) rowptr[node] = beg + excl;
    }
    __syncthreads();
    for (int p = tid; p < len; p += 256) {
        unsigned u = (p < CSR_CAP) ? lp[p] : staging[beg + p];
        int pos = atomicAdd(&lfill[(u >> 16) & 255], 1);
        src_sorted[beg + pos] = (int)(u & 0xFFFFu);
    }
}

// ---------------------------------------------------------------------------
// Fused per-destination aggregation: fp16 gather 16 B/lane, 2-wide unroll +
// src prefetch. Output fp16 (inter-layer) or fp32 (final), templated.
// ---------------------------------------------------------------------------
template <int F, bool RELU, typename OT>
__global__ __launch_bounds__(256) void gat_aggregate(
    const int* __restrict__ rowptr, const int* __restrict__ src_sorted,
    const __half* __restrict__ hh, const float* __restrict__ aS,
    const float* __restrict__ aD, const float* __restrict__ bias,
    OT* __restrict__ out, int N)
{
    constexpr int LPE = F / 8;          // lanes per edge (16 or 8)
    constexpr int EPW = 64 / LPE;       // edge slots per wave (4 or 8)

    const int i = blockIdx.x * 4 + (threadIdx.x >> 6);
    if (i >= N) return;
    const int lane = threadIdx.x & 63;
    const int sub = lane / LPE;
    const int l = lane % LPE;

    const float adi = aD[i];
    const int start = rowptr[i];
    const int end = rowptr[i + 1];

    float acc0[8], acc1[8];
#pragma unroll
    for (int q = 0; q < 8; q++) { acc0[q] = 0.f; acc1[q] = 0.f; }
    float den0 = 0.f, den1 = 0.f;

    int e0 = start + sub;
    int e1 = e0 + EPW;
    int s0 = (e0 < end) ? src_sorted[e0] : -1;
    int s1 = (e1 < end) ? src_sorted[e1] : -1;

    while (s0 >= 0) {
        int n0 = (e0 + 2 * EPW < end) ? src_sorted[e0 + 2 * EPW] : -1;
        int n1 = (e1 + 2 * EPW < end) ? src_sorted[e1 + 2 * EPW] : -1;
        {
            float w = __expf(leaky(aS[s0] + adi));
            uint4 u = *(const uint4*)(hh + (size_t)s0 * F + l * 8);
            const __half2* hp = (const __half2*)&u;
#pragma unroll
            for (int q = 0; q < 4; q++) {
                float2 f = __half22float2(hp[q]);
                acc0[q * 2]     += w * f.x;
                acc0[q * 2 + 1] += w * f.y;
            }
            den0 += w;
        }
        if (s1 >= 0) {
            float w = __expf(leaky(aS[s1] + adi));
            uint4 u = *(const uint4*)(hh + (size_t)s1 * F + l * 8);
            const __half2* hp = (const __half2*)&u;
#pragma unroll
            for (int q = 0; q < 4; q++) {
                float2 f = __half22float2(hp[q]);
                acc1[q * 2]     += w * f.x;
                acc1[q * 2 + 1] += w * f.y;
            }
            den1 += w;
        }
        e0 += 2 * EPW; e1 += 2 * EPW;
        s0 = n0; s1 = n1;
    }

    float acc[8];
#pragma unroll
    for (int q = 0; q < 8; q++) acc[q] = acc0[q] + acc1[q];
    float denom = den0 + den1;

#pragma unroll
    for (int off = 32; off >= LPE; off >>= 1) {
#pragma unroll
        for (int q = 0; q < 8; q++) acc[q] += __shfl_down(acc[q], off);
        denom += __shfl_down(denom, off);
    }

    if (sub == 0) {
        float wsf = __expf(leaky(aS[i] + adi));
        uint4 u = *(const uint4*)(hh + (size_t)i * F + l * 8);
        const __half2* hp = (const __half2*)&u;
        float inv = 1.f / (denom + wsf);
        float4 b0 = *(const float4*)(bias + l * 8);
        float4 b1 = *(const float4*)(bias + l * 8 + 4);
        float o[8];
#pragma unroll
        for (int q = 0; q < 4; q++) {
            float2 f = __half22float2(hp[q]);
            o[q * 2]     = (acc[q * 2]     + wsf * f.x) * inv;
            o[q * 2 + 1] = (acc[q * 2 + 1] + wsf * f.y) * inv;
        }
        o[0] += b0.x; o[1] += b0.y; o[2] += b0.z; o[3] += b0.w;
        o[4] += b1.x; o[5] += b1.y; o[6] += b1.z; o[7] += b1.w;
        if (RELU) {
#pragma unroll
            for (int q = 0; q < 8; q++) o[q] = fmaxf(o[q], 0.f);
        }
        if constexpr (sizeof(OT) == 2) {
            __half2 qh[4];
            qh[0] = __floats2half2_rn(o[0], o[1]);
            qh[1] = __floats2half2_rn(o[2], o[3]);
            qh[2] = __floats2half2_rn(o[4], o[5]);
            qh[3] = __floats2half2_rn(o[6], o[7]);
            *(uint4*)((__half*)out + (size_t)i * F + l * 8) = *(uint4*)qh;
        } else {
            *(float4*)((float*)out + (size_t)i * F + l * 8)     = make_float4(o[0], o[1], o[2], o[3]);
            *(float4*)((float*)out + (size_t)i * F + l * 8 + 4) = make_float4(o[4], o[5], o[6], o[7]);
        }
    }
}

extern "C" void kernel_launch(void* const* d_in, const int* in_sizes, int n_in,
                              void* d_out, int out_size, void* d_ws, size_t ws_size,
                              hipStream_t stream)
{
    const float* x   = (const float*)d_in[0];
    const int*   ei  = (const int*)d_in[1];
    const float* W1  = (const float*)d_in[2];
    const float* aS1 = (const float*)d_in[3];
    const float* aD1 = (const float*)d_in[4];
    const float* b1  = (const float*)d_in[5];
    const float* W2  = (const float*)d_in[6];
    const float* aS2 = (const float*)d_in[7];
    const float* aD2 = (const float*)d_in[8];
    const float* b2  = (const float*)d_in[9];

    const int K = 128, F1 = 128, F2 = 64;
    const int N = in_sizes[0] / K;   // 50000 (< 65536: packed u32 staging valid)
    const int E = in_sizes[1] / 2;
    const int* src = ei;
    const int* dst = ei + E;

    const int Np = (N + 4) & ~3;
    const int NB = (N + 255) >> 8;              // buckets of 256 nodes
    const int nbt = (E + TILE - 1) / TILE;      // edge tiles

    char* wsb = (char*)d_ws;
    int* gcnt         = (int*)wsb;      wsb += 256 * 4;           // zeroed (1 KB)
    int* gstart       = (int*)wsb;      wsb += 264 * 4;
    int* gfill        = (int*)wsb;      wsb += 256 * 4;
    int* rowptr       = (int*)wsb;      wsb += (size_t)(Np + 4) * 4;
    unsigned* staging = (unsigned*)wsb; wsb += (size_t)E * 4;
    int* src_sorted   = (int*)wsb;      wsb += (size_t)E * 4;
    __half* hh1       = (__half*)wsb;   wsb += (size_t)N * F1 * 2;
    __half* x2h       = (__half*)wsb;   wsb += (size_t)N * F1 * 2;
    __half* hh2       = (__half*)wsb;   wsb += (size_t)N * F2 * 2;
    float* as_        = (float*)wsb;    wsb += (size_t)Np * 4;
    float* ad_        = (float*)wsb;    wsb += (size_t)Np * 4;

    hipMemsetAsync(gcnt, 0, 256 * 4, stream);

    dim3 blk(256);

    // ---- layer-1 GEMM ----
    gemm_alpha<F1, float><<<dim3((N + 63) / 64), dim3(256), 0, stream>>>(
        x, W1, aS1, aD1, hh1, as_, ad_, N);

    // ---- CSR build (R5 structure, packed u32) ----
    bucket_count<<<dim3(nbt), blk, 0, stream>>>(dst, gcnt, E);
    bucket_scan<<<dim3(1), blk, 0, stream>>>(gcnt, gstart, gfill, NB, rowptr + N, E);
    bucket_scatter<<<dim3(nbt), blk, 0, stream>>>(src, dst, gfill, staging, E);
    bucket_to_csr<<<dim3(NB), blk, 0, stream>>>(staging, gstart, rowptr, src_sorted, N);

    // ---- layer 1 aggregate -> fp16 x2 ----
    gat_aggregate<F1, true, __half><<<dim3((N + 3) / 4), blk, 0, stream>>>(
        rowptr, src_sorted, hh1, as_, ad_, b1, x2h, N);

    // ---- layer 2 ----
    gemm_alpha<F2, __half><<<dim3((N + 63) / 64), dim3(128), 0, stream>>>(
        x2h, W2, aS2, aD2, hh2, as_, ad_, N);
    gat_aggregate<F2, false, float><<<dim3((N + 3) / 4), blk, 0, stream>>>(
        rowptr, src_sorted, hh2, as_, ad_, b2, (float*)d_out, N);
}

// Round 9
// 202.299 us; speedup vs baseline: 1.4331x; 1.1230x over previous
//
#include <hip/hip_runtime.h>
#include <hip/hip_fp16.h>
#include <cstddef>

#define NEG_SLOPE 0.2f
#define TILE 4096
#define CSR_CAP 6144

typedef _Float16 h8 __attribute__((ext_vector_type(8)));
typedef _Float16 h4 __attribute__((ext_vector_type(4)));
typedef float f4 __attribute__((ext_vector_type(4)));

__device__ __forceinline__ float leaky(float x) { return x >= 0.f ? x : NEG_SLOPE * x; }

__device__ __forceinline__ int wave_iscan(int v, int lane) {
#pragma unroll
    for (int off = 1; off < 64; off <<= 1) {
        int t = __shfl_up(v, off);
        if (lane >= off) v += t;
    }
    return v;
}

// ---------------------------------------------------------------------------
// MFMA GEMM + fused alpha dots. h = x @ W (x: [N,128], W: [128,F] fp32 rm),
// hh = fp16(h). K=128 staged entirely in LDS (fp16): As [64][136], Wt [F][136]
// (transposed+cast). 4 waves; wave w computes rows [w*16, w*16+16) x F cols.
// MFMA 16x16x32_f16 fragment layouts (m89/m120-verified):
//   A: lane holds A[m=lane&15][k=(lane>>4)*8+j], j=0..7
//   B: lane holds B[k=(lane>>4)*8+j][n=lane&15]
//   D: lane reg r holds D[row=(lane>>4)*4+r][col=lane&15]
// ---------------------------------------------------------------------------
template <int F, typename IT>
__global__ __launch_bounds__(256) void gemm_mfma(
    const IT* __restrict__ x, const float* __restrict__ W,
    const float* __restrict__ a_s, const float* __restrict__ a_d,
    _Float16* __restrict__ hh, float* __restrict__ alphaS, float* __restrict__ alphaD,
    int N)
{
    constexpr int K = 128;
    constexpr int LDK = K + 8;          // 136: keeps 16B alignment, staggers banks
    constexpr int NT = F / 16;          // col tiles (8 or 4)

    __shared__ _Float16 As[64 * LDK];
    __shared__ _Float16 Wt[F * LDK];

    const int tid = threadIdx.x;
    const int wave = tid >> 6;
    const int lane = tid & 63;
    const int q = lane >> 4;            // k-quad / row-quad
    const int c = lane & 15;            // A row / B col / D col
    const int rowb = blockIdx.x * 64;

    // ---- stage x -> As (fp16) ----
    if constexpr (sizeof(IT) == 4) {
        for (int i = tid; i < 64 * (K / 4); i += 256) {
            int r = i >> 5, c4 = i & 31;
            int gr = rowb + r;
            float4 v = (gr < N) ? *(const float4*)((const float*)x + (size_t)gr * K + c4 * 4)
                                : make_float4(0.f, 0.f, 0.f, 0.f);
            h4 hv = { (_Float16)v.x, (_Float16)v.y, (_Float16)v.z, (_Float16)v.w };
            *(h4*)(As + r * LDK + c4 * 4) = hv;
        }
    } else {
        for (int i = tid; i < 64 * (K / 8); i += 256) {
            int r = i >> 4, c8 = i & 15;
            int gr = rowb + r;
            h8 v;
            if (gr < N) v = *(const h8*)((const _Float16*)x + (size_t)gr * K + c8 * 8);
            else        v = (h8)(_Float16)0.f;
            *(h8*)(As + r * LDK + c8 * 8) = v;
        }
    }
    // ---- stage W -> Wt transposed (fp16) ----
    for (int i = tid; i < K * F; i += 256) {
        int k = i / F, n = i % F;
        Wt[n * LDK + k] = (_Float16)W[i];
    }
    __syncthreads();

    f4 acc[NT];
#pragma unroll
    for (int nt = 0; nt < NT; nt++) acc[nt] = (f4)0.f;

    const _Float16* aw = As + (wave * 16 + c) * LDK + q * 8;
#pragma unroll
    for (int kt = 0; kt < 4; kt++) {
        h8 af = *(const h8*)(aw + kt * 32);
#pragma unroll
        for (int nt = 0; nt < NT; nt++) {
            h8 bf = *(const h8*)(Wt + (nt * 16 + c) * LDK + kt * 32 + q * 8);
            acc[nt] = __builtin_amdgcn_mfma_f32_16x16x32_f16(af, bf, acc[nt], 0, 0, 0);
        }
    }

    // ---- epilogue: store fp16 h + fused alpha dot products ----
    float asl[NT], adl[NT];
#pragma unroll
    for (int nt = 0; nt < NT; nt++) {
        asl[nt] = a_s[nt * 16 + c];
        adl[nt] = a_d[nt * 16 + c];
    }
    const int row0 = rowb + wave * 16 + q * 4;
#pragma unroll
    for (int r = 0; r < 4; r++) {
        int row = row0 + r;
        if (row < N) {                      // uniform within the 16-lane group
            float ps = 0.f, pd = 0.f;
#pragma unroll
            for (int nt = 0; nt < NT; nt++) {
                float v = acc[nt][r];
                hh[(size_t)row * F + nt * 16 + c] = (_Float16)v;
                ps += v * asl[nt];
                pd += v * adl[nt];
            }
#pragma unroll
            for (int off = 8; off >= 1; off >>= 1) {
                ps += __shfl_down(ps, off, 16);
                pd += __shfl_down(pd, off, 16);
            }
            if (c == 0) { alphaS[row] = ps; alphaD[row] = pd; }
        }
    }
}

// ---------------------------------------------------------------------------
// CSR build (R5/R8 structure, packed u32 staging: (dst<<16)|src; N < 65536).
// ---------------------------------------------------------------------------
__global__ __launch_bounds__(256) void bucket_count(
    const int* __restrict__ dst, int* __restrict__ gcnt, int E)
{
    __shared__ int lcnt[256];
    const int tid = threadIdx.x;
    const int base = blockIdx.x * TILE;
    lcnt[tid] = 0;
    __syncthreads();
#pragma unroll
    for (int j = 0; j < TILE / 256; j++) {
        int idx = base + j * 256 + tid;
        if (idx < E) atomicAdd(&lcnt[dst[idx] >> 8], 1);
    }
    __syncthreads();
    int c = lcnt[tid];
    if (c > 0) atomicAdd(&gcnt[tid], c);
}

__global__ __launch_bounds__(256) void bucket_scan(
    const int* __restrict__ gcnt, int* __restrict__ gstart,
    int* __restrict__ gfill, int NB, int* __restrict__ rowptrN, int E)
{
    __shared__ int ws[4];
    int tid = threadIdx.x, lane = tid & 63, wid = tid >> 6;
    int v = (tid < NB) ? gcnt[tid] : 0;
    int incl = wave_iscan(v, lane);
    if (lane == 63) ws[wid] = incl;
    __syncthreads();
    int woff = 0;
    for (int w = 0; w < wid; w++) woff += ws[w];
    int excl = woff + incl - v;
    if (tid <= NB) gstart[tid] = excl;
    if (tid < NB) gfill[tid] = excl;
    if (tid == 0) *rowptrN = E;
}

__global__ __launch_bounds__(256) void bucket_scatter(
    const int* __restrict__ src, const int* __restrict__ dst,
    int* __restrict__ gfill, unsigned* __restrict__ staging, int E)
{
    __shared__ int lcnt[256];
    __shared__ int loff[256];
    __shared__ int gbase[256];
    __shared__ int ws[4];
    __shared__ unsigned pairs[TILE];
    __shared__ unsigned char bkt[TILE];

    const int tid = threadIdx.x;
    const int base = blockIdx.x * TILE;
    const int vt = min(TILE, E - base);

    lcnt[tid] = 0;
    __syncthreads();

    int d[TILE / 256], s[TILE / 256], r[TILE / 256];
#pragma unroll
    for (int j = 0; j < TILE / 256; j++) {
        int idx = base + j * 256 + tid;
        if (idx < E) {
            d[j] = dst[idx]; s[j] = src[idx];
            r[j] = atomicAdd(&lcnt[d[j] >> 8], 1);
        } else d[j] = -1;
    }
    __syncthreads();
    {
        int lane = tid & 63, wid = tid >> 6;
        int v = lcnt[tid];
        int incl = wave_iscan(v, lane);
        if (lane == 63) ws[wid] = incl;
        __syncthreads();
        int woff = 0;
        for (int w = 0; w < wid; w++) woff += ws[w];
        loff[tid] = woff + incl - v;
    }
    __syncthreads();
    {
        int c = lcnt[tid];
        if (c > 0) gbase[tid] = atomicAdd(&gfill[tid], c);
    }
    __syncthreads();
#pragma unroll
    for (int j = 0; j < TILE / 256; j++) {
        if (d[j] >= 0) {
            int b = d[j] >> 8;
            int slot = loff[b] + r[j];
            pairs[slot] = ((unsigned)d[j] << 16) | (unsigned)s[j];
            bkt[slot] = (unsigned char)b;
        }
    }
    __syncthreads();
    for (int slot = tid; slot < vt; slot += 256) {
        int b = bkt[slot];
        staging[gbase[b] + (slot - loff[b])] = pairs[slot];
    }
}

__global__ __launch_bounds__(256) void bucket_to_csr(
    const unsigned* __restrict__ staging, const int* __restrict__ gstart,
    int* __restrict__ rowptr, int* __restrict__ src_sorted, int N)
{
    __shared__ unsigned lp[CSR_CAP];
    __shared__ int lcnt[256], loff[256], lfill[256];
    __shared__ int ws[4];
    const int tid = threadIdx.x;
    const int b = blockIdx.x;
    const int beg = gstart[b], end = gstart[b + 1];
    const int len = end - beg;

    lcnt[tid] = 0;
    __syncthreads();
    for (int p = tid; p < len; p += 256) {
        unsigned u = staging[beg + p];
        if (p < CSR_CAP) lp[p] = u;
        atomicAdd(&lcnt[(u >> 16) & 255], 1);
    }
    __syncthreads();
    {
        int lane = tid & 63, wid = tid >> 6;
        int v = lcnt[tid];
        int incl = wave_iscan(v, lane);
        if (lane == 63) ws[wid] = incl;
        __syncthreads();
        int woff = 0;
        for (int w = 0; w < wid; w++) woff += ws[w];
        int excl = woff + incl - v;
        loff[tid] = excl;
        lfill[tid] = excl;
        int node = (b << 8) + tid;
        if (node < N) rowptr[node] = beg + excl;
    }
    __syncthreads();
    for (int p = tid; p < len; p += 256) {
        unsigned u = (p < CSR_CAP) ? lp[p] : staging[beg + p];
        int pos = atomicAdd(&lfill[(u >> 16) & 255], 1);
        src_sorted[beg + pos] = (int)(u & 0xFFFFu);
    }
}

// ---------------------------------------------------------------------------
// Fused per-destination aggregation: fp16 gather 16 B/lane, 2-wide unroll +
// src prefetch. Output fp16 (inter-layer) or fp32 (final), templated.
// ---------------------------------------------------------------------------
template <int F, bool RELU, typename OT>
__global__ __launch_bounds__(256) void gat_aggregate(
    const int* __restrict__ rowptr, const int* __restrict__ src_sorted,
    const __half* __restrict__ hh, const float* __restrict__ aS,
    const float* __restrict__ aD, const float* __restrict__ bias,
    OT* __restrict__ out, int N)
{
    constexpr int LPE = F / 8;          // lanes per edge (16 or 8)
    constexpr int EPW = 64 / LPE;       // edge slots per wave (4 or 8)

    const int i = blockIdx.x * 4 + (threadIdx.x >> 6);
    if (i >= N) return;
    const int lane = threadIdx.x & 63;
    const int sub = lane / LPE;
    const int l = lane % LPE;

    const float adi = aD[i];
    const int start = rowptr[i];
    const int end = rowptr[i + 1];

    float acc0[8], acc1[8];
#pragma unroll
    for (int q = 0; q < 8; q++) { acc0[q] = 0.f; acc1[q] = 0.f; }
    float den0 = 0.f, den1 = 0.f;

    int e0 = start + sub;
    int e1 = e0 + EPW;
    int s0 = (e0 < end) ? src_sorted[e0] : -1;
    int s1 = (e1 < end) ? src_sorted[e1] : -1;

    while (s0 >= 0) {
        int n0 = (e0 + 2 * EPW < end) ? src_sorted[e0 + 2 * EPW] : -1;
        int n1 = (e1 + 2 * EPW < end) ? src_sorted[e1 + 2 * EPW] : -1;
        {
            float w = __expf(leaky(aS[s0] + adi));
            uint4 u = *(const uint4*)(hh + (size_t)s0 * F + l * 8);
            const __half2* hp = (const __half2*)&u;
#pragma unroll
            for (int q = 0; q < 4; q++) {
                float2 f = __half22float2(hp[q]);
                acc0[q * 2]     += w * f.x;
                acc0[q * 2 + 1] += w * f.y;
            }
            den0 += w;
        }
        if (s1 >= 0) {
            float w = __expf(leaky(aS[s1] + adi));
            uint4 u = *(const uint4*)(hh + (size_t)s1 * F + l * 8);
            const __half2* hp = (const __half2*)&u;
#pragma unroll
            for (int q = 0; q < 4; q++) {
                float2 f = __half22float2(hp[q]);
                acc1[q * 2]     += w * f.x;
                acc1[q * 2 + 1] += w * f.y;
            }
            den1 += w;
        }
        e0 += 2 * EPW; e1 += 2 * EPW;
        s0 = n0; s1 = n1;
    }

    float acc[8];
#pragma unroll
    for (int q = 0; q < 8; q++) acc[q] = acc0[q] + acc1[q];
    float denom = den0 + den1;

#pragma unroll
    for (int off = 32; off >= LPE; off >>= 1) {
#pragma unroll
        for (int q = 0; q < 8; q++) acc[q] += __shfl_down(acc[q], off);
        denom += __shfl_down(denom, off);
    }

    if (sub == 0) {
        float wsf = __expf(leaky(aS[i] + adi));
        uint4 u = *(const uint4*)(hh + (size_t)i * F + l * 8);
        const __half2* hp = (const __half2*)&u;
        float inv = 1.f / (denom + wsf);
        float4 b0 = *(const float4*)(bias + l * 8);
        float4 b1 = *(const float4*)(bias + l * 8 + 4);
        float o[8];
#pragma unroll
        for (int q = 0; q < 4; q++) {
            float2 f = __half22float2(hp[q]);
            o[q * 2]     = (acc[q * 2]     + wsf * f.x) * inv;
            o[q * 2 + 1] = (acc[q * 2 + 1] + wsf * f.y) * inv;
        }
        o[0] += b0.x; o[1] += b0.y; o[2] += b0.z; o[3] += b0.w;
        o[4] += b1.x; o[5] += b1.y; o[6] += b1.z; o[7] += b1.w;
        if (RELU) {
#pragma unroll
            for (int q = 0; q < 8; q++) o[q] = fmaxf(o[q], 0.f);
        }
        if constexpr (sizeof(OT) == 2) {
            __half2 qh[4];
            qh[0] = __floats2half2_rn(o[0], o[1]);
            qh[1] = __floats2half2_rn(o[2], o[3]);
            qh[2] = __floats2half2_rn(o[4], o[5]);
            qh[3] = __floats2half2_rn(o[6], o[7]);
            *(uint4*)((__half*)out + (size_t)i * F + l * 8) = *(uint4*)qh;
        } else {
            *(float4*)((float*)out + (size_t)i * F + l * 8)     = make_float4(o[0], o[1], o[2], o[3]);
            *(float4*)((float*)out + (size_t)i * F + l * 8 + 4) = make_float4(o[4], o[5], o[6], o[7]);
        }
    }
}

extern "C" void kernel_launch(void* const* d_in, const int* in_sizes, int n_in,
                              void* d_out, int out_size, void* d_ws, size_t ws_size,
                              hipStream_t stream)
{
    const float* x   = (const float*)d_in[0];
    const int*   ei  = (const int*)d_in[1];
    const float* W1  = (const float*)d_in[2];
    const float* aS1 = (const float*)d_in[3];
    const float* aD1 = (const float*)d_in[4];
    const float* b1  = (const float*)d_in[5];
    const float* W2  = (const float*)d_in[6];
    const float* aS2 = (const float*)d_in[7];
    const float* aD2 = (const float*)d_in[8];
    const float* b2  = (const float*)d_in[9];

    const int K = 128, F1 = 128, F2 = 64;
    const int N = in_sizes[0] / K;   // 50000 (< 65536: packed u32 staging valid)
    const int E = in_sizes[1] / 2;
    const int* src = ei;
    const int* dst = ei + E;

    const int Np = (N + 4) & ~3;
    const int NB = (N + 255) >> 8;
    const int nbt = (E + TILE - 1) / TILE;

    char* wsb = (char*)d_ws;
    int* gcnt         = (int*)wsb;      wsb += 256 * 4;           // zeroed (1 KB)
    int* gstart       = (int*)wsb;      wsb += 264 * 4;
    int* gfill        = (int*)wsb;      wsb += 256 * 4;
    int* rowptr       = (int*)wsb;      wsb += (size_t)(Np + 4) * 4;
    unsigned* staging = (unsigned*)wsb; wsb += (size_t)E * 4;
    int* src_sorted   = (int*)wsb;      wsb += (size_t)E * 4;
    _Float16* hh1     = (_Float16*)wsb; wsb += (size_t)N * F1 * 2;
    _Float16* x2h     = (_Float16*)wsb; wsb += (size_t)N * F1 * 2;
    _Float16* hh2     = (_Float16*)wsb; wsb += (size_t)N * F2 * 2;
    float* as_        = (float*)wsb;    wsb += (size_t)Np * 4;
    float* ad_        = (float*)wsb;    wsb += (size_t)Np * 4;

    hipMemsetAsync(gcnt, 0, 256 * 4, stream);

    dim3 blk(256);

    // ---- layer-1 GEMM (MFMA) ----
    gemm_mfma<F1, float><<<dim3((N + 63) / 64), blk, 0, stream>>>(
        x, W1, aS1, aD1, hh1, as_, ad_, N);

    // ---- CSR build ----
    bucket_count<<<dim3(nbt), blk, 0, stream>>>(dst, gcnt, E);
    bucket_scan<<<dim3(1), blk, 0, stream>>>(gcnt, gstart, gfill, NB, rowptr + N, E);
    bucket_scatter<<<dim3(nbt), blk, 0, stream>>>(src, dst, gfill, staging, E);
    bucket_to_csr<<<dim3(NB), blk, 0, stream>>>(staging, gstart, rowptr, src_sorted, N);

    // ---- layer 1 aggregate -> fp16 x2 ----
    gat_aggregate<F1, true, __half><<<dim3((N + 3) / 4), blk, 0, stream>>>(
        rowptr, src_sorted, (const __half*)hh1, as_, ad_, b1, (__half*)x2h, N);

    // ---- layer 2 ----
    gemm_mfma<F2, _Float16><<<dim3((N + 63) / 64), blk, 0, stream>>>(
        x2h, W2, aS2, aD2, hh2, as_, ad_, N);
    gat_aggregate<F2, false, float><<<dim3((N + 3) / 4), blk, 0, stream>>>(
        rowptr, src_sorted, (const __half*)hh2, as_, ad_, b2, (float*)d_out, N);
}

// Round 10
// 201.536 us; speedup vs baseline: 1.4385x; 1.0038x over previous
//
#include <hip/hip_runtime.h>
#include <hip/hip_fp16.h>
#include <cstddef>

#define NEG_SLOPE 0.2f
#define TILE 4096
#define CSR_CAP 6144

typedef _Float16 h8 __attribute__((ext_vector_type(8)));
typedef _Float16 h4 __attribute__((ext_vector_type(4)));
typedef float f4 __attribute__((ext_vector_type(4)));

__device__ __forceinline__ float leaky(float x) { return x >= 0.f ? x : NEG_SLOPE * x; }

__device__ __forceinline__ int wave_iscan(int v, int lane) {
#pragma unroll
    for (int off = 1; off < 64; off <<= 1) {
        int t = __shfl_up(v, off);
        if (lane >= off) v += t;
    }
    return v;
}

// ---------------------------------------------------------------------------
// MFMA GEMM + fused alpha dots. h = x @ W (x: [N,128], W: [128,F] fp32 rm),
// hh = fp16(h). K=128 staged entirely in LDS (fp16).
// ---------------------------------------------------------------------------
template <int F, typename IT>
__global__ __launch_bounds__(256) void gemm_mfma(
    const IT* __restrict__ x, const float* __restrict__ W,
    const float* __restrict__ a_s, const float* __restrict__ a_d,
    _Float16* __restrict__ hh, float* __restrict__ alphaS, float* __restrict__ alphaD,
    int N)
{
    constexpr int K = 128;
    constexpr int LDK = K + 8;
    constexpr int NT = F / 16;

    __shared__ _Float16 As[64 * LDK];
    __shared__ _Float16 Wt[F * LDK];

    const int tid = threadIdx.x;
    const int wave = tid >> 6;
    const int lane = tid & 63;
    const int q = lane >> 4;
    const int c = lane & 15;
    const int rowb = blockIdx.x * 64;

    if constexpr (sizeof(IT) == 4) {
        for (int i = tid; i < 64 * (K / 4); i += 256) {
            int r = i >> 5, c4 = i & 31;
            int gr = rowb + r;
            float4 v = (gr < N) ? *(const float4*)((const float*)x + (size_t)gr * K + c4 * 4)
                                : make_float4(0.f, 0.f, 0.f, 0.f);
            h4 hv = { (_Float16)v.x, (_Float16)v.y, (_Float16)v.z, (_Float16)v.w };
            *(h4*)(As + r * LDK + c4 * 4) = hv;
        }
    } else {
        for (int i = tid; i < 64 * (K / 8); i += 256) {
            int r = i >> 4, c8 = i & 15;
            int gr = rowb + r;
            h8 v;
            if (gr < N) v = *(const h8*)((const _Float16*)x + (size_t)gr * K + c8 * 8);
            else        v = (h8)(_Float16)0.f;
            *(h8*)(As + r * LDK + c8 * 8) = v;
        }
    }
    for (int i = tid; i < K * F; i += 256) {
        int k = i / F, n = i % F;
        Wt[n * LDK + k] = (_Float16)W[i];
    }
    __syncthreads();

    f4 acc[NT];
#pragma unroll
    for (int nt = 0; nt < NT; nt++) acc[nt] = (f4)0.f;

    const _Float16* aw = As + (wave * 16 + c) * LDK + q * 8;
#pragma unroll
    for (int kt = 0; kt < 4; kt++) {
        h8 af = *(const h8*)(aw + kt * 32);
#pragma unroll
        for (int nt = 0; nt < NT; nt++) {
            h8 bf = *(const h8*)(Wt + (nt * 16 + c) * LDK + kt * 32 + q * 8);
            acc[nt] = __builtin_amdgcn_mfma_f32_16x16x32_f16(af, bf, acc[nt], 0, 0, 0);
        }
    }

    float asl[NT], adl[NT];
#pragma unroll
    for (int nt = 0; nt < NT; nt++) {
        asl[nt] = a_s[nt * 16 + c];
        adl[nt] = a_d[nt * 16 + c];
    }
    const int row0 = rowb + wave * 16 + q * 4;
#pragma unroll
    for (int r = 0; r < 4; r++) {
        int row = row0 + r;
        if (row < N) {
            float ps = 0.f, pd = 0.f;
#pragma unroll
            for (int nt = 0; nt < NT; nt++) {
                float v = acc[nt][r];
                hh[(size_t)row * F + nt * 16 + c] = (_Float16)v;
                ps += v * asl[nt];
                pd += v * adl[nt];
            }
#pragma unroll
            for (int off = 8; off >= 1; off >>= 1) {
                ps += __shfl_down(ps, off, 16);
                pd += __shfl_down(pd, off, 16);
            }
            if (c == 0) { alphaS[row] = ps; alphaD[row] = pd; }
        }
    }
}

// ---------------------------------------------------------------------------
// CSR build (packed u32 staging: (dst<<16)|src; N < 65536). bucket = dst>>8.
// ---------------------------------------------------------------------------
__global__ __launch_bounds__(256) void bucket_count(
    const int* __restrict__ dst, int* __restrict__ gcnt, int E)
{
    __shared__ int lcnt[256];
    const int tid = threadIdx.x;
    const int base = blockIdx.x * TILE;
    lcnt[tid] = 0;
    __syncthreads();
#pragma unroll
    for (int j = 0; j < TILE / 256; j++) {
        int idx = base + j * 256 + tid;
        if (idx < E) atomicAdd(&lcnt[dst[idx] >> 8], 1);
    }
    __syncthreads();
    int c = lcnt[tid];
    if (c > 0) atomicAdd(&gcnt[tid], c);
}

__global__ __launch_bounds__(256) void bucket_scan(
    const int* __restrict__ gcnt, int* __restrict__ gstart,
    int* __restrict__ gfill, int NB, int* __restrict__ rowptrN, int E)
{
    __shared__ int ws[4];
    int tid = threadIdx.x, lane = tid & 63, wid = tid >> 6;
    int v = (tid < NB) ? gcnt[tid] : 0;
    int incl = wave_iscan(v, lane);
    if (lane == 63) ws[wid] = incl;
    __syncthreads();
    int woff = 0;
    for (int w = 0; w < wid; w++) woff += ws[w];
    int excl = woff + incl - v;
    if (tid <= NB) gstart[tid] = excl;
    if (tid < NB) gfill[tid] = excl;
    if (tid == 0) *rowptrN = E;
}

__global__ __launch_bounds__(256) void bucket_scatter(
    const int* __restrict__ src, const int* __restrict__ dst,
    int* __restrict__ gfill, unsigned* __restrict__ staging, int E)
{
    __shared__ int lcnt[256];
    __shared__ int loff[256];
    __shared__ int gbase[256];
    __shared__ int ws[4];
    __shared__ unsigned pairs[TILE];
    __shared__ unsigned char bkt[TILE];

    const int tid = threadIdx.x;
    const int base = blockIdx.x * TILE;
    const int vt = min(TILE, E - base);

    lcnt[tid] = 0;
    __syncthreads();

    int d[TILE / 256], s[TILE / 256], r[TILE / 256];
#pragma unroll
    for (int j = 0; j < TILE / 256; j++) {
        int idx = base + j * 256 + tid;
        if (idx < E) {
            d[j] = dst[idx]; s[j] = src[idx];
            r[j] = atomicAdd(&lcnt[d[j] >> 8], 1);
        } else d[j] = -1;
    }
    __syncthreads();
    {
        int lane = tid & 63, wid = tid >> 6;
        int v = lcnt[tid];
        int incl = wave_iscan(v, lane);
        if (lane == 63) ws[wid] = incl;
        __syncthreads();
        int woff = 0;
        for (int w = 0; w < wid; w++) woff += ws[w];
        loff[tid] = woff + incl - v;
    }
    __syncthreads();
    {
        int c = lcnt[tid];
        if (c > 0) gbase[tid] = atomicAdd(&gfill[tid], c);
    }
    __syncthreads();
#pragma unroll
    for (int j = 0; j < TILE / 256; j++) {
        if (d[j] >= 0) {
            int b = d[j] >> 8;
            int slot = loff[b] + r[j];
            pairs[slot] = ((unsigned)d[j] << 16) | (unsigned)s[j];
            bkt[slot] = (unsigned char)b;
        }
    }
    __syncthreads();
    for (int slot = tid; slot < vt; slot += 256) {
        int b = bkt[slot];
        staging[gbase[b] + (slot - loff[b])] = pairs[slot];
    }
}

__global__ __launch_bounds__(256) void bucket_to_csr(
    const unsigned* __restrict__ staging, const int* __restrict__ gstart,
    int* __restrict__ rowptr, int* __restrict__ src_sorted, int N)
{
    __shared__ unsigned lp[CSR_CAP];
    __shared__ int lcnt[256], loff[256], lfill[256];
    __shared__ int ws[4];
    const int tid = threadIdx.x;
    const int b = blockIdx.x;
    const int beg = gstart[b], end = gstart[b + 1];
    const int len = end - beg;

    lcnt[tid] = 0;
    __syncthreads();
    for (int p = tid; p < len; p += 256) {
        unsigned u = staging[beg + p];
        if (p < CSR_CAP) lp[p] = u;
        atomicAdd(&lcnt[(u >> 16) & 255], 1);
    }
    __syncthreads();
    {
        int lane = tid & 63, wid = tid >> 6;
        int v = lcnt[tid];
        int incl = wave_iscan(v, lane);
        if (lane == 63) ws[wid] = incl;
        __syncthreads();
        int woff = 0;
        for (int w = 0; w < wid; w++) woff += ws[w];
        int excl = woff + incl - v;
        loff[tid] = excl;
        lfill[tid] = excl;
        int node = (b << 8) + tid;
        if (node < N) rowptr[node] = beg + excl;
    }
    __syncthreads();
    for (int p = tid; p < len; p += 256) {
        unsigned u = (p < CSR_CAP) ? lp[p] : staging[beg + p];
        int pos = atomicAdd(&lfill[(u >> 16) & 255], 1);
        src_sorted[beg + pos] = (int)(u & 0xFFFFu);
    }
}

// ---------------------------------------------------------------------------
// Fused per-destination aggregation: fp16 gather 16 B/lane, 4-stream edge
// unroll with index prefetch (≈16 edges in flight per wave at F=128).
// ---------------------------------------------------------------------------
template <int F, bool RELU, typename OT>
__global__ __launch_bounds__(256) void gat_aggregate(
    const int* __restrict__ rowptr, const int* __restrict__ src_sorted,
    const __half* __restrict__ hh, const float* __restrict__ aS,
    const float* __restrict__ aD, const float* __restrict__ bias,
    OT* __restrict__ out, int N)
{
    constexpr int LPE = F / 8;          // lanes per edge (16 or 8)
    constexpr int EPW = 64 / LPE;       // edge slots per wave (4 or 8)

    const int i = blockIdx.x * 4 + (threadIdx.x >> 6);
    if (i >= N) return;
    const int lane = threadIdx.x & 63;
    const int sub = lane / LPE;
    const int l = lane % LPE;

    const float adi = aD[i];
    const int start = rowptr[i];
    const int end = rowptr[i + 1];

    float accA[8], accB[8];
#pragma unroll
    for (int q = 0; q < 8; q++) { accA[q] = 0.f; accB[q] = 0.f; }
    float denA = 0.f, denB = 0.f;

    int e = start + sub;
    int s0 = (e + 0 * EPW < end) ? src_sorted[e + 0 * EPW] : -1;
    int s1 = (e + 1 * EPW < end) ? src_sorted[e + 1 * EPW] : -1;
    int s2 = (e + 2 * EPW < end) ? src_sorted[e + 2 * EPW] : -1;
    int s3 = (e + 3 * EPW < end) ? src_sorted[e + 3 * EPW] : -1;

    while (s0 >= 0) {
        int eb = e + 4 * EPW;
        int n0 = (eb + 0 * EPW < end) ? src_sorted[eb + 0 * EPW] : -1;
        int n1 = (eb + 1 * EPW < end) ? src_sorted[eb + 1 * EPW] : -1;
        int n2 = (eb + 2 * EPW < end) ? src_sorted[eb + 2 * EPW] : -1;
        int n3 = (eb + 3 * EPW < end) ? src_sorted[eb + 3 * EPW] : -1;

        {
            float w = __expf(leaky(aS[s0] + adi));
            uint4 u = *(const uint4*)(hh + (size_t)s0 * F + l * 8);
            const __half2* hp = (const __half2*)&u;
#pragma unroll
            for (int q = 0; q < 4; q++) {
                float2 f = __half22float2(hp[q]);
                accA[q * 2]     += w * f.x;
                accA[q * 2 + 1] += w * f.y;
            }
            denA += w;
        }
        if (s1 >= 0) {
            float w = __expf(leaky(aS[s1] + adi));
            uint4 u = *(const uint4*)(hh + (size_t)s1 * F + l * 8);
            const __half2* hp = (const __half2*)&u;
#pragma unroll
            for (int q = 0; q < 4; q++) {
                float2 f = __half22float2(hp[q]);
                accB[q * 2]     += w * f.x;
                accB[q * 2 + 1] += w * f.y;
            }
            denB += w;
        }
        if (s2 >= 0) {
            float w = __expf(leaky(aS[s2] + adi));
            uint4 u = *(const uint4*)(hh + (size_t)s2 * F + l * 8);
            const __half2* hp = (const __half2*)&u;
#pragma unroll
            for (int q = 0; q < 4; q++) {
                float2 f = __half22float2(hp[q]);
                accA[q * 2]     += w * f.x;
                accA[q * 2 + 1] += w * f.y;
            }
            denA += w;
        }
        if (s3 >= 0) {
            float w = __expf(leaky(aS[s3] + adi));
            uint4 u = *(const uint4*)(hh + (size_t)s3 * F + l * 8);
            const __half2* hp = (const __half2*)&u;
#pragma unroll
            for (int q = 0; q < 4; q++) {
                float2 f = __half22float2(hp[q]);
                accB[q * 2]     += w * f.x;
                accB[q * 2 + 1] += w * f.y;
            }
            denB += w;
        }
        e = eb;
        s0 = n0; s1 = n1; s2 = n2; s3 = n3;
    }

    float acc[8];
#pragma unroll
    for (int q = 0; q < 8; q++) acc[q] = accA[q] + accB[q];
    float denom = denA + denB;

#pragma unroll
    for (int off = 32; off >= LPE; off >>= 1) {
#pragma unroll
        for (int q = 0; q < 8; q++) acc[q] += __shfl_down(acc[q], off);
        denom += __shfl_down(denom, off);
    }

    if (sub == 0) {
        float wsf = __expf(leaky(aS[i] + adi));
        uint4 u = *(const uint4*)(hh + (size_t)i * F + l * 8);
        const __half2* hp = (const __half2*)&u;
        float inv = 1.f / (denom + wsf);
        float4 b0 = *(const float4*)(bias + l * 8);
        float4 b1 = *(const float4*)(bias + l * 8 + 4);
        float o[8];
#pragma unroll
        for (int q = 0; q < 4; q++) {
            float2 f = __half22float2(hp[q]);
            o[q * 2]     = (acc[q * 2]     + wsf * f.x) * inv;
            o[q * 2 + 1] = (acc[q * 2 + 1] + wsf * f.y) * inv;
        }
        o[0] += b0.x; o[1] += b0.y; o[2] += b0.z; o[3] += b0.w;
        o[4] += b1.x; o[5] += b1.y; o[6] += b1.z; o[7] += b1.w;
        if (RELU) {
#pragma unroll
            for (int q = 0; q < 8; q++) o[q] = fmaxf(o[q], 0.f);
        }
        if constexpr (sizeof(OT) == 2) {
            __half2 qh[4];
            qh[0] = __floats2half2_rn(o[0], o[1]);
            qh[1] = __floats2half2_rn(o[2], o[3]);
            qh[2] = __floats2half2_rn(o[4], o[5]);
            qh[3] = __floats2half2_rn(o[6], o[7]);
            *(uint4*)((__half*)out + (size_t)i * F + l * 8) = *(uint4*)qh;
        } else {
            *(float4*)((float*)out + (size_t)i * F + l * 8)     = make_float4(o[0], o[1], o[2], o[3]);
            *(float4*)((float*)out + (size_t)i * F + l * 8 + 4) = make_float4(o[4], o[5], o[6], o[7]);
        }
    }
}

extern "C" void kernel_launch(void* const* d_in, const int* in_sizes, int n_in,
                              void* d_out, int out_size, void* d_ws, size_t ws_size,
                              hipStream_t stream)
{
    const float* x   = (const float*)d_in[0];
    const int*   ei  = (const int*)d_in[1];
    const float* W1  = (const float*)d_in[2];
    const float* aS1 = (const float*)d_in[3];
    const float* aD1 = (const float*)d_in[4];
    const float* b1  = (const float*)d_in[5];
    const float* W2  = (const float*)d_in[6];
    const float* aS2 = (const float*)d_in[7];
    const float* aD2 = (const float*)d_in[8];
    const float* b2  = (const float*)d_in[9];

    const int K = 128, F1 = 128, F2 = 64;
    const int N = in_sizes[0] / K;   // 50000 (< 65536: packed u32 staging valid)
    const int E = in_sizes[1] / 2;
    const int* src = ei;
    const int* dst = ei + E;

    const int Np = (N + 4) & ~3;
    const int NB = (N + 255) >> 8;
    const int nbt = (E + TILE - 1) / TILE;

    char* wsb = (char*)d_ws;
    int* gcnt         = (int*)wsb;      wsb += 256 * 4;           // zeroed (1 KB)
    int* gstart       = (int*)wsb;      wsb += 264 * 4;
    int* gfill        = (int*)wsb;      wsb += 256 * 4;
    int* rowptr       = (int*)wsb;      wsb += (size_t)(Np + 4) * 4;
    unsigned* staging = (unsigned*)wsb; wsb += (size_t)E * 4;
    int* src_sorted   = (int*)wsb;      wsb += (size_t)E * 4;
    _Float16* hh1     = (_Float16*)wsb; wsb += (size_t)N * F1 * 2;
    _Float16* x2h     = (_Float16*)wsb; wsb += (size_t)N * F1 * 2;
    _Float16* hh2     = (_Float16*)wsb; wsb += (size_t)N * F2 * 2;
    float* as_        = (float*)wsb;    wsb += (size_t)Np * 4;
    float* ad_        = (float*)wsb;    wsb += (size_t)Np * 4;

    hipMemsetAsync(gcnt, 0, 256 * 4, stream);

    dim3 blk(256);

    // ---- layer-1 GEMM (MFMA) ----
    gemm_mfma<F1, float><<<dim3((N + 63) / 64), blk, 0, stream>>>(
        x, W1, aS1, aD1, hh1, as_, ad_, N);

    // ---- CSR build ----
    bucket_count<<<dim3(nbt), blk, 0, stream>>>(dst, gcnt, E);
    bucket_scan<<<dim3(1), blk, 0, stream>>>(gcnt, gstart, gfill, NB, rowptr + N, E);
    bucket_scatter<<<dim3(nbt), blk, 0, stream>>>(src, dst, gfill, staging, E);
    bucket_to_csr<<<dim3(NB), blk, 0, stream>>>(staging, gstart, rowptr, src_sorted, N);

    // ---- layer 1 aggregate -> fp16 x2 ----
    gat_aggregate<F1, true, __half><<<dim3((N + 3) / 4), blk, 0, stream>>>(
        rowptr, src_sorted, (const __half*)hh1, as_, ad_, b1, (__half*)x2h, N);

    // ---- layer 2 ----
    gemm_mfma<F2, _Float16><<<dim3((N + 63) / 64), blk, 0, stream>>>(
        x2h, W2, aS2, aD2, hh2, as_, ad_, N);
    gat_aggregate<F2, false, float><<<dim3((N + 3) / 4), blk, 0, stream>>>(
        rowptr, src_sorted, (const __half*)hh2, as_, ad_, b2, (float*)d_out, N);
}